// Round 4
// baseline (492.325 us; speedup 1.0000x reference)
//
#include <hip/hip_runtime.h>
#include <stdint.h>

// Channel attention (Restormer MDTA style). R3: inputs/outputs are FP32
// (confirmed by R2 on-device diagnostic: sentinel 50 => x has NaN as bf16).
// Internal compute: bf16 MFMA with fp32 accumulation (threshold is
// bf16-tolerant: 2.59e-2, floor_eps_k=8).
// Per chunk of G batches (G adaptive from ws_size; R2 proved ws >= 33.5MB):
//   transpose_f2b : x[b][c][p] f32 -> XT[b][p][c] bf16   (region1)
//   gemm_bt<bf16> : qkv_pre = Wqkv_bf . XT               (M=576,N=16384,K=192)
//   dwconv qk     : qkv_pre ch[0,384) -> qk_post bf16    (region1, XT dead)
//   dwconv v      : qkv_pre ch[384,576) -> v_post        (class-0 slots of qkv_pre)
//   attn_scores   : S[bh] += q.k^T, norms += diag MFMA   (fp32 in ws)
//   softmax       : attn = softmax(temp * S / (|q||k|))
//   mproj         : Mm[b] = W_proj . blockdiag(attn)     (bf16)
//   transpose_b   : v_post -> vT                         (class-1 slots)
//   gemm_bt<f32>  : out = Mm . vT -> d_out fp32          (M=192,N=16384,K=192)

typedef __attribute__((ext_vector_type(8))) short bf16x8;
typedef __attribute__((ext_vector_type(4))) float f32x4;
typedef unsigned short u16;

#define HW 16384
#define CD 192
#define O3 576
#define KD 192

__device__ __forceinline__ float b2f(u16 u) {
    union { unsigned int i; float f; } v; v.i = ((unsigned int)u) << 16; return v.f;
}
__device__ __forceinline__ u16 f2b(float f) {
    union { float f; unsigned int i; } v; v.f = f;
    return (u16)((v.i + 0x7fffu + ((v.i >> 16) & 1u)) >> 16);  // RNE
}

__global__ __launch_bounds__(256) void fill_f32(float* p, long long n, float val) {
    long long stride = (long long)gridDim.x * 256;
    for (long long i = blockIdx.x * 256LL + threadIdx.x; i < n; i += stride) p[i] = val;
}

__global__ __launch_bounds__(256) void zerof(float* p, int n) {
    int i = blockIdx.x * 256 + threadIdx.x;
    if (i < n) p[i] = 0.f;
}

__global__ __launch_bounds__(256) void cvt_f2b(const float* __restrict__ in,
                                               u16* __restrict__ out, int n) {
    int i = blockIdx.x * 256 + threadIdx.x;
    if (i < n) out[i] = f2b(in[i]);
}

// x[b][c][p] fp32 (ch stride HW) -> XT[b][p][c] bf16 (row stride CD). 64x64 tiles.
__global__ __launch_bounds__(256) void transpose_f2b(
    const float* __restrict__ in, u16* __restrict__ out,
    long long in_bs, long long out_bs)
{
    __shared__ u16 t[64 * 72];
    const int tid = threadIdx.x;
    const int p0 = blockIdx.x * 64, c0 = blockIdx.y * 64;
    const long long bz = blockIdx.z;
    const float* ib = in + bz * in_bs;
    u16* ob = out + bz * out_bs;
    {
        int cl = tid >> 2, pc = (tid & 3) * 16;
        const float* src = &ib[(long long)(c0 + cl) * HW + p0 + pc];
#pragma unroll
        for (int j4 = 0; j4 < 4; j4++) {
            f32x4 v = *(const f32x4*)(src + j4 * 4);
            u16* d = &t[cl * 72 + pc + j4 * 4];
            d[0] = f2b(v[0]); d[1] = f2b(v[1]); d[2] = f2b(v[2]); d[3] = f2b(v[3]);
        }
    }
    __syncthreads();
    {
        int pl = tid >> 2, cc = (tid & 3) * 16;
        u16 tmp[16] __attribute__((aligned(16)));
#pragma unroll
        for (int j = 0; j < 16; j++) tmp[j] = t[(cc + j) * 72 + pl];
        u16* dst = &ob[(long long)(p0 + pl) * CD + c0 + cc];
        *(bf16x8*)dst       = *(const bf16x8*)&tmp[0];
        *(bf16x8*)(dst + 8) = *(const bf16x8*)&tmp[8];
    }
}

// bf16 -> bf16 transpose (for v)
__global__ __launch_bounds__(256) void transpose_b(
    const u16* __restrict__ in, u16* __restrict__ out,
    long long in_bs, long long out_bs)
{
    __shared__ u16 t[64 * 72];
    const int tid = threadIdx.x;
    const int p0 = blockIdx.x * 64, c0 = blockIdx.y * 64;
    const long long bz = blockIdx.z;
    const u16* ib = in + bz * in_bs;
    u16* ob = out + bz * out_bs;
    {
        int cl = tid >> 2, pc = (tid & 3) * 16;
        const u16* src = &ib[(long long)(c0 + cl) * HW + p0 + pc];
        *(bf16x8*)&t[cl * 72 + pc]     = *(const bf16x8*)src;
        *(bf16x8*)&t[cl * 72 + pc + 8] = *(const bf16x8*)(src + 8);
    }
    __syncthreads();
    {
        int pl = tid >> 2, cc = (tid & 3) * 16;
        u16 tmp[16] __attribute__((aligned(16)));
#pragma unroll
        for (int j = 0; j < 16; j++) tmp[j] = t[(cc + j) * 72 + pl];
        u16* dst = &ob[(long long)(p0 + pl) * CD + c0 + cc];
        *(bf16x8*)dst       = *(const bf16x8*)&tmp[0];
        *(bf16x8*)(dst + 8) = *(const bf16x8*)&tmp[8];
    }
}

__device__ __forceinline__ void stage16(const u16* g, u16* l, int lane) {
    *(bf16x8*)(l + lane * 8) = *(const bf16x8*)g;
}

// C[b][m][n] = sum_k A[b][m][k]*Bt[b][n][k]; bf16 in, fp32 acc.
// OUT_F32: store fp32, else bf16. 128x128 tile, BK=32, 4 waves of 64x64.
template <bool OUT_F32>
__global__ __launch_bounds__(256) void gemm_bt(
    const u16* __restrict__ A, const u16* __restrict__ Bt, void* __restrict__ Cv,
    int M, long long a_bs, long long b_bs, long long c_bs)
{
    __shared__ u16 lsA[128 * 32];
    __shared__ u16 lsB[128 * 32];
    const int tid = threadIdx.x;
    const int lane = tid & 63, wid = tid >> 6;
    const int n0 = blockIdx.x * 128, m0 = blockIdx.y * 128;
    const long long bz = blockIdx.z;
    const u16* Ab = A + bz * a_bs;
    const u16* Bb = Bt + bz * b_bs;
    const int wm = (wid & 1) * 64, wn = (wid >> 1) * 64;
    const int lr = lane & 15, quad = lane >> 4;
    const int srow = lane >> 2, skc = (lane & 3) * 8;

    f32x4 acc[4][4];
#pragma unroll
    for (int i = 0; i < 4; i++)
#pragma unroll
        for (int j = 0; j < 4; j++) acc[i][j] = (f32x4){0.f, 0.f, 0.f, 0.f};

    for (int k0 = 0; k0 < KD; k0 += 32) {
        __syncthreads();
#pragma unroll
        for (int i = 0; i < 2; i++) {
            int ra = m0 + wid * 32 + i * 16 + srow;
            ra = ra < M ? ra : M - 1;  // clamp; rows >= M discarded at store
            stage16(Ab + (long long)ra * KD + k0 + skc, &lsA[(wid * 32 + i * 16) * 32], lane);
            int rb = n0 + wid * 32 + i * 16 + srow;
            stage16(Bb + (long long)rb * KD + k0 + skc, &lsB[(wid * 32 + i * 16) * 32], lane);
        }
        __syncthreads();
        bf16x8 af[4], bfv[4];
#pragma unroll
        for (int t = 0; t < 4; t++) {
            af[t]  = *(const bf16x8*)&lsA[(wm + t * 16 + lr) * 32 + quad * 8];
            bfv[t] = *(const bf16x8*)&lsB[(wn + t * 16 + lr) * 32 + quad * 8];
        }
#pragma unroll
        for (int mt = 0; mt < 4; mt++)
#pragma unroll
            for (int nt = 0; nt < 4; nt++)
                acc[mt][nt] = __builtin_amdgcn_mfma_f32_16x16x32_bf16(af[mt], bfv[nt], acc[mt][nt], 0, 0, 0);
    }
    // C/D layout: col = lane&15, row = quad*4 + reg
#pragma unroll
    for (int mt = 0; mt < 4; mt++)
#pragma unroll
        for (int r = 0; r < 4; r++) {
            int row = m0 + wm + mt * 16 + quad * 4 + r;
            if (row < M) {
#pragma unroll
                for (int nt = 0; nt < 4; nt++) {
                    int col = n0 + wn + nt * 16 + lr;
                    if (OUT_F32)
                        ((float*)Cv)[bz * c_bs + (long long)row * HW + col] = acc[mt][nt][r];
                    else
                        ((u16*)Cv)[bz * c_bs + (long long)row * HW + col] = f2b(acc[mt][nt][r]);
                }
            }
        }
}

// depthwise 3x3 SAME; in/out bf16, weights fp32.
__global__ __launch_bounds__(256) void dwconv(
    const u16* __restrict__ in, const float* __restrict__ wdw, u16* __restrict__ outp,
    long long in_bs, long long out_bs)
{
    const int rt = blockIdx.x, ch = blockIdx.y, tid = threadIdx.x;
    const long long bz = blockIdx.z;
    const u16* ip = in + bz * in_bs + (long long)ch * HW;
    u16* op = outp + bz * out_bs + (long long)ch * HW;
    __shared__ u16 t[18 * 128];
    const int r0 = rt * 16;
    for (int i = tid; i < 18 * 128; i += 256) {
        int rr = i >> 7, cc = i & 127;
        int gr = r0 + rr - 1;
        t[i] = (gr >= 0 && gr < 128) ? ip[gr * 128 + cc] : (u16)0;
    }
    float w[9];
#pragma unroll
    for (int j = 0; j < 9; j++) w[j] = wdw[ch * 9 + j];
    __syncthreads();
#pragma unroll
    for (int jj = 0; jj < 8; jj++) {
        int pix = tid + jj * 256;
        int rr = pix >> 7, cc = pix & 127;
        float acc = 0.f;
#pragma unroll
        for (int dy = 0; dy < 3; dy++)
#pragma unroll
            for (int dx = 0; dx < 3; dx++) {
                int c2 = cc + dx - 1;
                float xv = (c2 >= 0 && c2 < 128) ? b2f(t[(rr + dy) * 128 + c2]) : 0.f;
                acc += w[dy * 3 + dx] * xv;
            }
        op[(long long)(r0 + rr) * 128 + cc] = f2b(acc);
    }
}

// S[bh][48][48] += q.k^T ; norms[bh][96] += diag(q.q^T), diag(k.k^T)
// qk layout: [b][384ch][HW], q = ch[0,192), k = ch[192,384). grid (16,4,G).
__global__ __launch_bounds__(256) void attn_scores(
    const u16* __restrict__ qk, float* __restrict__ S, float* __restrict__ norms,
    int bh0)
{
    const int tid = threadIdx.x, lane = tid & 63, wid = tid >> 6;
    const int kc = blockIdx.x, head = blockIdx.y;
    const long long bz = blockIdx.z;
    const u16* q = qk + bz * (2LL * CD * HW) + (long long)head * 48 * HW;
    const u16* k = q + (long long)CD * HW;
    const int lr = lane & 15, quad = lane >> 4;

    f32x4 sc[3][3], sq[3], sk[3];
#pragma unroll
    for (int i = 0; i < 3; i++) {
#pragma unroll
        for (int j = 0; j < 3; j++) sc[i][j] = (f32x4){0.f, 0.f, 0.f, 0.f};
        sq[i] = (f32x4){0.f, 0.f, 0.f, 0.f};
        sk[i] = (f32x4){0.f, 0.f, 0.f, 0.f};
    }
    const int n0 = kc * 1024 + wid * 256;
#pragma unroll 2
    for (int s = 0; s < 8; s++) {
        const int n = n0 + s * 32 + quad * 8;
        bf16x8 aq[3], ak[3];
#pragma unroll
        for (int t3 = 0; t3 < 3; t3++) {
            aq[t3] = *(const bf16x8*)(q + (long long)(t3 * 16 + lr) * HW + n);
            ak[t3] = *(const bf16x8*)(k + (long long)(t3 * 16 + lr) * HW + n);
        }
#pragma unroll
        for (int mt = 0; mt < 3; mt++)
#pragma unroll
            for (int nt = 0; nt < 3; nt++)
                sc[mt][nt] = __builtin_amdgcn_mfma_f32_16x16x32_bf16(aq[mt], ak[nt], sc[mt][nt], 0, 0, 0);
#pragma unroll
        for (int t3 = 0; t3 < 3; t3++) {
            sq[t3] = __builtin_amdgcn_mfma_f32_16x16x32_bf16(aq[t3], aq[t3], sq[t3], 0, 0, 0);
            sk[t3] = __builtin_amdgcn_mfma_f32_16x16x32_bf16(ak[t3], ak[t3], sk[t3], 0, 0, 0);
        }
    }
    __shared__ float sS[2304];
    __shared__ float snq[48], snk[48];
    for (int i = tid; i < 2304; i += 256) sS[i] = 0.f;
    if (tid < 48) { snq[tid] = 0.f; snk[tid] = 0.f; }
    __syncthreads();
#pragma unroll
    for (int mt = 0; mt < 3; mt++)
#pragma unroll
        for (int nt = 0; nt < 3; nt++)
#pragma unroll
            for (int r = 0; r < 4; r++)
                atomicAdd(&sS[(mt * 16 + quad * 4 + r) * 48 + nt * 16 + lr], sc[mt][nt][r]);
#pragma unroll
    for (int t3 = 0; t3 < 3; t3++)
#pragma unroll
        for (int r = 0; r < 4; r++) {
            int rw = quad * 4 + r;
            if (rw == lr) {
                atomicAdd(&snq[t3 * 16 + rw], sq[t3][r]);
                atomicAdd(&snk[t3 * 16 + rw], sk[t3][r]);
            }
        }
    __syncthreads();
    const int bh = bh0 + (int)bz * 4 + head;
    float* Sg = S + (long long)bh * 2304;
    for (int i = tid; i < 2304; i += 256) atomicAdd(&Sg[i], sS[i]);
    float* ng = norms + bh * 96;
    if (tid < 48) atomicAdd(&ng[tid], snq[tid]);
    else if (tid < 96) atomicAdd(&ng[tid], snk[tid - 48]);
}

__global__ __launch_bounds__(64) void softmax_k(
    const float* __restrict__ S, const float* __restrict__ norms,
    const float* __restrict__ temp, float* __restrict__ attn, int bh0)
{
    const int bh = bh0 + blockIdx.x, head = bh & 3, r = threadIdx.x;
    if (r >= 48) return;
    const float tv = temp[head];
    const float* Sg = S + (long long)bh * 2304;
    const float* ng = norms + bh * 96;
    const float nq = fmaxf(sqrtf(ng[r]), 1e-12f);
    float lg[48];
    float mx = -1e30f;
#pragma unroll
    for (int d = 0; d < 48; d++) {
        float nk = fmaxf(sqrtf(ng[48 + d]), 1e-12f);
        float v = Sg[r * 48 + d] * tv / (nq * nk);
        lg[d] = v; mx = fmaxf(mx, v);
    }
    float sum = 0.f;
#pragma unroll
    for (int d = 0; d < 48; d++) { float e = __expf(lg[d] - mx); lg[d] = e; sum += e; }
    const float inv = 1.f / sum;
    float* Ag = attn + (long long)bh * 2304 + r * 48;
#pragma unroll
    for (int d = 0; d < 48; d++) Ag[d] = lg[d] * inv;
}

// Mm[b][o][h*48+d] = sum_c Wp[o][h*48+c] * attn[b][h][c][d]; Wp fp32, Mm bf16
__global__ __launch_bounds__(256) void mproj(
    const float* __restrict__ wproj, const float* __restrict__ attn, u16* __restrict__ Mm,
    int b0)
{
    const int ob = blockIdx.x, b = b0 + blockIdx.y, tid = threadIdx.x;
    __shared__ float sA[9216];
    const float* Ab = attn + (long long)b * 9216;
    for (int i = tid; i < 9216; i += 256) sA[i] = Ab[i];
    __syncthreads();
    for (int i = tid; i < 48 * 192; i += 256) {
        int o = ob * 48 + i / 192;
        int cc = i % 192;
        int h = cc / 48, d = cc - h * 48;
        const float* wr = wproj + o * 192 + h * 48;
        const float* ar = &sA[h * 2304 + d];
        float acc = 0.f;
        for (int c = 0; c < 48; c++) acc += wr[c] * ar[c * 48];
        Mm[(long long)b * 36864 + o * 192 + cc] = f2b(acc);
    }
}

extern "C" void kernel_launch(void* const* d_in, const int* in_sizes, int n_in,
                              void* d_out, int out_size, void* d_ws, size_t ws_size,
                              hipStream_t stream)
{
    const float* x     = (const float*)d_in[0];
    const float* wqkv  = (const float*)d_in[1];
    const float* wdw   = (const float*)d_in[2];
    const float* temp  = (const float*)d_in[3];
    const float* wproj = (const float*)d_in[4];
    float* out = (float*)d_out;
    char* ws = (char*)d_ws;
    const long long CHW = (long long)CD * HW;

    if (ws_size < 2097152ULL + 31457280ULL) {  // G=1 floor; R2 proved this passes
        fill_f32<<<2048, 256, 0, stream>>>(out, out_size, 100.0f);
        return;
    }
    int G = 8;
    while (G > 1 && (unsigned long long)(2097152ULL + (unsigned long long)G * 31457280ULL) > (unsigned long long)ws_size)
        G >>= 1;

    float* S      = (float*)ws;                // 32*2304 f32
    float* norms  = (float*)(ws + 294912);     // 32*96 f32
    float* attn   = (float*)(ws + 307200);     // 32*2304 f32
    u16*   Mm     = (u16*)(ws + 602112);       // 8*36864 bf16
    u16*   wqkv_b = (u16*)(ws + 1191936);      // 576*192 bf16
    u16* region1  = (u16*)(ws + 2097152);      // G*2CHW bf16
    u16* qkv_pre  = region1 + (long long)G * 2 * CHW;  // G*3CHW bf16

    zerof<<<300, 256, 0, stream>>>(S, 76800);  // S + norms contiguous
    cvt_f2b<<<432, 256, 0, stream>>>(wqkv, wqkv_b, O3 * KD);

    for (int g0 = 0; g0 < 8; g0 += G) {
        transpose_f2b<<<dim3(256, 3, G), 256, 0, stream>>>(
            x + (long long)g0 * CHW, region1, CHW, CHW);
        gemm_bt<false><<<dim3(128, 5, G), 256, 0, stream>>>(
            wqkv_b, region1, qkv_pre, O3, 0LL, CHW, 3LL * CHW);
        dwconv<<<dim3(8, 384, G), 256, 0, stream>>>(
            qkv_pre, wdw, region1, 3LL * CHW, 2LL * CHW);
        dwconv<<<dim3(8, 192, G), 256, 0, stream>>>(
            qkv_pre + 2LL * CHW, wdw + 384 * 9, qkv_pre, 3LL * CHW, 3LL * CHW);
        attn_scores<<<dim3(16, 4, G), 256, 0, stream>>>(region1, S, norms, g0 * 4);
        softmax_k<<<4 * G, 64, 0, stream>>>(S, norms, temp, attn, g0 * 4);
        mproj<<<dim3(4, G), 256, 0, stream>>>(wproj, attn, Mm, g0);
        transpose_b<<<dim3(256, 3, G), 256, 0, stream>>>(
            qkv_pre, qkv_pre + CHW, 3LL * CHW, 3LL * CHW);
        gemm_bt<true><<<dim3(128, 2, G), 256, 0, stream>>>(
            Mm + (long long)g0 * 36864, qkv_pre + CHW, out + (long long)g0 * CHW,
            CD, 36864LL, 3LL * CHW, CHW);
    }
}

// Round 5
// 435.050 us; speedup vs baseline: 1.1317x; 1.1317x over previous
//
#include <hip/hip_runtime.h>
#include <stdint.h>

// Channel attention (Restormer MDTA style). FP32 in/out, bf16 MFMA internals.
// R4: (1) dwconv rewritten — fp32 LDS tile with zero halo, vector ds_read_b128,
//     8 outputs/thread, conversion+bounds at staging only (was VALU-bound 70%);
//     (2) gemm_bt staging via __builtin_amdgcn_global_load_lds width=16 (m97).
// Pipeline per chunk of G batches (G adaptive; profile shows G=8 fits):
//   transpose_f2b : x[b][c][p] f32 -> XT[b][p][c] bf16   (region1)
//   gemm_bt<bf16> : qkv_pre = Wqkv_bf . XT               (M=576,N=16384,K=192)
//   dwconv2 qk    : qkv_pre ch[0,384) -> qk_post bf16    (region1, XT dead)
//   dwconv2 v     : qkv_pre ch[384,576) -> v_post        (class-0 slots of qkv_pre)
//   attn_scores   : S[bh] += q.k^T, norms += diag MFMA   (fp32 in ws)
//   softmax       : attn = softmax(temp * S / (|q||k|))
//   mproj         : Mm[b] = W_proj . blockdiag(attn)     (bf16)
//   transpose_b   : v_post -> vT                         (class-1 slots)
//   gemm_bt<f32>  : out = Mm . vT -> d_out fp32          (M=192,N=16384,K=192)

typedef __attribute__((ext_vector_type(8))) short bf16x8;
typedef __attribute__((ext_vector_type(4))) float f32x4;
typedef unsigned short u16;

#define HW 16384
#define CD 192
#define O3 576
#define KD 192

__device__ __forceinline__ float b2f(u16 u) {
    union { unsigned int i; float f; } v; v.i = ((unsigned int)u) << 16; return v.f;
}
__device__ __forceinline__ u16 f2b(float f) {
    union { float f; unsigned int i; } v; v.f = f;
    return (u16)((v.i + 0x7fffu + ((v.i >> 16) & 1u)) >> 16);  // RNE
}

__global__ __launch_bounds__(256) void fill_f32(float* p, long long n, float val) {
    long long stride = (long long)gridDim.x * 256;
    for (long long i = blockIdx.x * 256LL + threadIdx.x; i < n; i += stride) p[i] = val;
}

__global__ __launch_bounds__(256) void zerof(float* p, int n) {
    int i = blockIdx.x * 256 + threadIdx.x;
    if (i < n) p[i] = 0.f;
}

__global__ __launch_bounds__(256) void cvt_f2b(const float* __restrict__ in,
                                               u16* __restrict__ out, int n) {
    int i = blockIdx.x * 256 + threadIdx.x;
    if (i < n) out[i] = f2b(in[i]);
}

// x[b][c][p] fp32 (ch stride HW) -> XT[b][p][c] bf16 (row stride CD). 64x64 tiles.
__global__ __launch_bounds__(256) void transpose_f2b(
    const float* __restrict__ in, u16* __restrict__ out,
    long long in_bs, long long out_bs)
{
    __shared__ u16 t[64 * 72];
    const int tid = threadIdx.x;
    const int p0 = blockIdx.x * 64, c0 = blockIdx.y * 64;
    const long long bz = blockIdx.z;
    const float* ib = in + bz * in_bs;
    u16* ob = out + bz * out_bs;
    {
        int cl = tid >> 2, pc = (tid & 3) * 16;
        const float* src = &ib[(long long)(c0 + cl) * HW + p0 + pc];
#pragma unroll
        for (int j4 = 0; j4 < 4; j4++) {
            f32x4 v = *(const f32x4*)(src + j4 * 4);
            u16* d = &t[cl * 72 + pc + j4 * 4];
            d[0] = f2b(v[0]); d[1] = f2b(v[1]); d[2] = f2b(v[2]); d[3] = f2b(v[3]);
        }
    }
    __syncthreads();
    {
        int pl = tid >> 2, cc = (tid & 3) * 16;
        u16 tmp[16] __attribute__((aligned(16)));
#pragma unroll
        for (int j = 0; j < 16; j++) tmp[j] = t[(cc + j) * 72 + pl];
        u16* dst = &ob[(long long)(p0 + pl) * CD + c0 + cc];
        *(bf16x8*)dst       = *(const bf16x8*)&tmp[0];
        *(bf16x8*)(dst + 8) = *(const bf16x8*)&tmp[8];
    }
}

// bf16 -> bf16 transpose (for v)
__global__ __launch_bounds__(256) void transpose_b(
    const u16* __restrict__ in, u16* __restrict__ out,
    long long in_bs, long long out_bs)
{
    __shared__ u16 t[64 * 72];
    const int tid = threadIdx.x;
    const int p0 = blockIdx.x * 64, c0 = blockIdx.y * 64;
    const long long bz = blockIdx.z;
    const u16* ib = in + bz * in_bs;
    u16* ob = out + bz * out_bs;
    {
        int cl = tid >> 2, pc = (tid & 3) * 16;
        const u16* src = &ib[(long long)(c0 + cl) * HW + p0 + pc];
        *(bf16x8*)&t[cl * 72 + pc]     = *(const bf16x8*)src;
        *(bf16x8*)&t[cl * 72 + pc + 8] = *(const bf16x8*)(src + 8);
    }
    __syncthreads();
    {
        int pl = tid >> 2, cc = (tid & 3) * 16;
        u16 tmp[16] __attribute__((aligned(16)));
#pragma unroll
        for (int j = 0; j < 16; j++) tmp[j] = t[(cc + j) * 72 + pl];
        u16* dst = &ob[(long long)(p0 + pl) * CD + c0 + cc];
        *(bf16x8*)dst       = *(const bf16x8*)&tmp[0];
        *(bf16x8*)(dst + 8) = *(const bf16x8*)&tmp[8];
    }
}

// Async global->LDS staging, 16B/lane at wave-uniform base + lane*16 (m97).
__device__ __forceinline__ void stage16(const u16* g, u16* l) {
    __builtin_amdgcn_global_load_lds((const __attribute__((address_space(1))) unsigned int*)g,
                                     (__attribute__((address_space(3))) unsigned int*)l, 16, 0, 0);
}

// C[b][m][n] = sum_k A[b][m][k]*Bt[b][n][k]; bf16 in, fp32 acc.
// OUT_F32: store fp32, else bf16. 128x128 tile, BK=32, 4 waves of 64x64.
template <bool OUT_F32>
__global__ __launch_bounds__(256) void gemm_bt(
    const u16* __restrict__ A, const u16* __restrict__ Bt, void* __restrict__ Cv,
    int M, long long a_bs, long long b_bs, long long c_bs)
{
    __shared__ u16 lsA[128 * 32];
    __shared__ u16 lsB[128 * 32];
    const int tid = threadIdx.x;
    const int lane = tid & 63, wid = tid >> 6;
    const int n0 = blockIdx.x * 128, m0 = blockIdx.y * 128;
    const long long bz = blockIdx.z;
    const u16* Ab = A + bz * a_bs;
    const u16* Bb = Bt + bz * b_bs;
    const int wm = (wid & 1) * 64, wn = (wid >> 1) * 64;
    const int lr = lane & 15, quad = lane >> 4;
    const int srow = lane >> 2, skc = (lane & 3) * 8;

    f32x4 acc[4][4];
#pragma unroll
    for (int i = 0; i < 4; i++)
#pragma unroll
        for (int j = 0; j < 4; j++) acc[i][j] = (f32x4){0.f, 0.f, 0.f, 0.f};

    for (int k0 = 0; k0 < KD; k0 += 32) {
        __syncthreads();
#pragma unroll
        for (int i = 0; i < 2; i++) {
            int ra = m0 + wid * 32 + i * 16 + srow;
            ra = ra < M ? ra : M - 1;  // clamp; rows >= M discarded at store
            stage16(Ab + (long long)ra * KD + k0 + skc, &lsA[(wid * 32 + i * 16) * 32]);
            int rb = n0 + wid * 32 + i * 16 + srow;
            stage16(Bb + (long long)rb * KD + k0 + skc, &lsB[(wid * 32 + i * 16) * 32]);
        }
        __syncthreads();
        bf16x8 af[4], bfv[4];
#pragma unroll
        for (int t = 0; t < 4; t++) {
            af[t]  = *(const bf16x8*)&lsA[(wm + t * 16 + lr) * 32 + quad * 8];
            bfv[t] = *(const bf16x8*)&lsB[(wn + t * 16 + lr) * 32 + quad * 8];
        }
#pragma unroll
        for (int mt = 0; mt < 4; mt++)
#pragma unroll
            for (int nt = 0; nt < 4; nt++)
                acc[mt][nt] = __builtin_amdgcn_mfma_f32_16x16x32_bf16(af[mt], bfv[nt], acc[mt][nt], 0, 0, 0);
    }
    // C/D layout: col = lane&15, row = quad*4 + reg
#pragma unroll
    for (int mt = 0; mt < 4; mt++)
#pragma unroll
        for (int r = 0; r < 4; r++) {
            int row = m0 + wm + mt * 16 + quad * 4 + r;
            if (row < M) {
#pragma unroll
                for (int nt = 0; nt < 4; nt++) {
                    int col = n0 + wn + nt * 16 + lr;
                    if (OUT_F32)
                        ((float*)Cv)[bz * c_bs + (long long)row * HW + col] = acc[mt][nt][r];
                    else
                        ((u16*)Cv)[bz * c_bs + (long long)row * HW + col] = f2b(acc[mt][nt][r]);
                }
            }
        }
}

// depthwise 3x3 SAME; in/out bf16, weights fp32 (weight row = wch0 + ch).
// fp32 LDS tile 18x132 (zero halo cols), conversion+bounds at staging,
// 8 outputs/thread via aligned f32x4 LDS reads.
__global__ __launch_bounds__(256) void dwconv2(
    const u16* __restrict__ in, const float* __restrict__ wdw, u16* __restrict__ outp,
    long long in_bs, long long out_bs, int wch0)
{
    const int rt = blockIdx.x, ch = blockIdx.y, tid = threadIdx.x;
    const long long bz = blockIdx.z;
    const u16* ip = in + bz * in_bs + (long long)ch * HW;
    u16* op = outp + bz * out_bs + (long long)ch * HW;
    __shared__ float t[18 * 132];
    const int r0 = rt * 16;
    if (tid < 18) {
        t[tid * 132 + 0] = 0.f;   t[tid * 132 + 129] = 0.f;
        t[tid * 132 + 130] = 0.f; t[tid * 132 + 131] = 0.f;
    }
    for (int i = tid; i < 288; i += 256) {
        int rr = i >> 4, cc = (i & 15) * 8;
        int gr = r0 + rr - 1;
        float f[8];
        if (gr >= 0 && gr < 128) {
            bf16x8 v = *(const bf16x8*)(ip + gr * 128 + cc);
#pragma unroll
            for (int j = 0; j < 8; j++) f[j] = b2f((u16)v[j]);
        } else {
#pragma unroll
            for (int j = 0; j < 8; j++) f[j] = 0.f;
        }
#pragma unroll
        for (int j = 0; j < 8; j++) t[rr * 132 + 1 + cc + j] = f[j];
    }
    float w[9];
#pragma unroll
    for (int j = 0; j < 9; j++) w[j] = wdw[(wch0 + ch) * 9 + j];
    __syncthreads();
    const int rr = tid >> 4, c8 = (tid & 15) * 8;
    float o[8] = {0.f, 0.f, 0.f, 0.f, 0.f, 0.f, 0.f, 0.f};
#pragma unroll
    for (int dy = 0; dy < 3; dy++) {
        const float* row = &t[(rr + dy) * 132 + c8];  // LDS idx c8 == image col c8-1
        float r[12] __attribute__((aligned(16)));
        *(f32x4*)&r[0] = *(const f32x4*)row;
        *(f32x4*)&r[4] = *(const f32x4*)(row + 4);
        *(f32x4*)&r[8] = *(const f32x4*)(row + 8);
        const float w0 = w[dy * 3], w1 = w[dy * 3 + 1], w2 = w[dy * 3 + 2];
#pragma unroll
        for (int j = 0; j < 8; j++) o[j] += w0 * r[j] + w1 * r[j + 1] + w2 * r[j + 2];
    }
    u16 ob[8] __attribute__((aligned(16)));
#pragma unroll
    for (int j = 0; j < 8; j++) ob[j] = f2b(o[j]);
    *(bf16x8*)&op[(long long)(r0 + rr) * 128 + c8] = *(const bf16x8*)ob;
}

// S[bh][48][48] += q.k^T ; norms[bh][96] += diag(q.q^T), diag(k.k^T)
// qk layout: [b][384ch][HW], q = ch[0,192), k = ch[192,384). grid (16,4,G).
__global__ __launch_bounds__(256) void attn_scores(
    const u16* __restrict__ qk, float* __restrict__ S, float* __restrict__ norms,
    int bh0)
{
    const int tid = threadIdx.x, lane = tid & 63, wid = tid >> 6;
    const int kc = blockIdx.x, head = blockIdx.y;
    const long long bz = blockIdx.z;
    const u16* q = qk + bz * (2LL * CD * HW) + (long long)head * 48 * HW;
    const u16* k = q + (long long)CD * HW;
    const int lr = lane & 15, quad = lane >> 4;

    f32x4 sc[3][3], sq[3], sk[3];
#pragma unroll
    for (int i = 0; i < 3; i++) {
#pragma unroll
        for (int j = 0; j < 3; j++) sc[i][j] = (f32x4){0.f, 0.f, 0.f, 0.f};
        sq[i] = (f32x4){0.f, 0.f, 0.f, 0.f};
        sk[i] = (f32x4){0.f, 0.f, 0.f, 0.f};
    }
    const int n0 = kc * 1024 + wid * 256;
#pragma unroll 2
    for (int s = 0; s < 8; s++) {
        const int n = n0 + s * 32 + quad * 8;
        bf16x8 aq[3], ak[3];
#pragma unroll
        for (int t3 = 0; t3 < 3; t3++) {
            aq[t3] = *(const bf16x8*)(q + (long long)(t3 * 16 + lr) * HW + n);
            ak[t3] = *(const bf16x8*)(k + (long long)(t3 * 16 + lr) * HW + n);
        }
#pragma unroll
        for (int mt = 0; mt < 3; mt++)
#pragma unroll
            for (int nt = 0; nt < 3; nt++)
                sc[mt][nt] = __builtin_amdgcn_mfma_f32_16x16x32_bf16(aq[mt], ak[nt], sc[mt][nt], 0, 0, 0);
#pragma unroll
        for (int t3 = 0; t3 < 3; t3++) {
            sq[t3] = __builtin_amdgcn_mfma_f32_16x16x32_bf16(aq[t3], aq[t3], sq[t3], 0, 0, 0);
            sk[t3] = __builtin_amdgcn_mfma_f32_16x16x32_bf16(ak[t3], ak[t3], sk[t3], 0, 0, 0);
        }
    }
    __shared__ float sS[2304];
    __shared__ float snq[48], snk[48];
    for (int i = tid; i < 2304; i += 256) sS[i] = 0.f;
    if (tid < 48) { snq[tid] = 0.f; snk[tid] = 0.f; }
    __syncthreads();
#pragma unroll
    for (int mt = 0; mt < 3; mt++)
#pragma unroll
        for (int nt = 0; nt < 3; nt++)
#pragma unroll
            for (int r = 0; r < 4; r++)
                atomicAdd(&sS[(mt * 16 + quad * 4 + r) * 48 + nt * 16 + lr], sc[mt][nt][r]);
#pragma unroll
    for (int t3 = 0; t3 < 3; t3++)
#pragma unroll
        for (int r = 0; r < 4; r++) {
            int rw = quad * 4 + r;
            if (rw == lr) {
                atomicAdd(&snq[t3 * 16 + rw], sq[t3][r]);
                atomicAdd(&snk[t3 * 16 + rw], sk[t3][r]);
            }
        }
    __syncthreads();
    const int bh = bh0 + (int)bz * 4 + head;
    float* Sg = S + (long long)bh * 2304;
    for (int i = tid; i < 2304; i += 256) atomicAdd(&Sg[i], sS[i]);
    float* ng = norms + bh * 96;
    if (tid < 48) atomicAdd(&ng[tid], snq[tid]);
    else if (tid < 96) atomicAdd(&ng[tid], snk[tid - 48]);
}

__global__ __launch_bounds__(64) void softmax_k(
    const float* __restrict__ S, const float* __restrict__ norms,
    const float* __restrict__ temp, float* __restrict__ attn, int bh0)
{
    const int bh = bh0 + blockIdx.x, head = bh & 3, r = threadIdx.x;
    if (r >= 48) return;
    const float tv = temp[head];
    const float* Sg = S + (long long)bh * 2304;
    const float* ng = norms + bh * 96;
    const float nq = fmaxf(sqrtf(ng[r]), 1e-12f);
    float lg[48];
    float mx = -1e30f;
#pragma unroll
    for (int d = 0; d < 48; d++) {
        float nk = fmaxf(sqrtf(ng[48 + d]), 1e-12f);
        float v = Sg[r * 48 + d] * tv / (nq * nk);
        lg[d] = v; mx = fmaxf(mx, v);
    }
    float sum = 0.f;
#pragma unroll
    for (int d = 0; d < 48; d++) { float e = __expf(lg[d] - mx); lg[d] = e; sum += e; }
    const float inv = 1.f / sum;
    float* Ag = attn + (long long)bh * 2304 + r * 48;
#pragma unroll
    for (int d = 0; d < 48; d++) Ag[d] = lg[d] * inv;
}

// Mm[b][o][h*48+d] = sum_c Wp[o][h*48+c] * attn[b][h][c][d]; Wp fp32, Mm bf16
__global__ __launch_bounds__(256) void mproj(
    const float* __restrict__ wproj, const float* __restrict__ attn, u16* __restrict__ Mm,
    int b0)
{
    const int ob = blockIdx.x, b = b0 + blockIdx.y, tid = threadIdx.x;
    __shared__ float sA[9216];
    const float* Ab = attn + (long long)b * 9216;
    for (int i = tid; i < 9216; i += 256) sA[i] = Ab[i];
    __syncthreads();
    for (int i = tid; i < 48 * 192; i += 256) {
        int o = ob * 48 + i / 192;
        int cc = i % 192;
        int h = cc / 48, d = cc - h * 48;
        const float* wr = wproj + o * 192 + h * 48;
        const float* ar = &sA[h * 2304 + d];
        float acc = 0.f;
        for (int c = 0; c < 48; c++) acc += wr[c] * ar[c * 48];
        Mm[(long long)b * 36864 + o * 192 + cc] = f2b(acc);
    }
}

extern "C" void kernel_launch(void* const* d_in, const int* in_sizes, int n_in,
                              void* d_out, int out_size, void* d_ws, size_t ws_size,
                              hipStream_t stream)
{
    const float* x     = (const float*)d_in[0];
    const float* wqkv  = (const float*)d_in[1];
    const float* wdw   = (const float*)d_in[2];
    const float* temp  = (const float*)d_in[3];
    const float* wproj = (const float*)d_in[4];
    float* out = (float*)d_out;
    char* ws = (char*)d_ws;
    const long long CHW = (long long)CD * HW;

    if (ws_size < 2097152ULL + 31457280ULL) {  // G=1 floor (proved present)
        fill_f32<<<2048, 256, 0, stream>>>(out, out_size, 100.0f);
        return;
    }
    int G = 8;
    while (G > 1 && (unsigned long long)(2097152ULL + (unsigned long long)G * 31457280ULL) > (unsigned long long)ws_size)
        G >>= 1;

    float* S      = (float*)ws;                // 32*2304 f32
    float* norms  = (float*)(ws + 294912);     // 32*96 f32
    float* attn   = (float*)(ws + 307200);     // 32*2304 f32
    u16*   Mm     = (u16*)(ws + 602112);       // 8*36864 bf16
    u16*   wqkv_b = (u16*)(ws + 1191936);      // 576*192 bf16
    u16* region1  = (u16*)(ws + 2097152);      // G*2CHW bf16
    u16* qkv_pre  = region1 + (long long)G * 2 * CHW;  // G*3CHW bf16

    zerof<<<300, 256, 0, stream>>>(S, 76800);  // S + norms contiguous
    cvt_f2b<<<432, 256, 0, stream>>>(wqkv, wqkv_b, O3 * KD);

    for (int g0 = 0; g0 < 8; g0 += G) {
        transpose_f2b<<<dim3(256, 3, G), 256, 0, stream>>>(
            x + (long long)g0 * CHW, region1, CHW, CHW);
        gemm_bt<false><<<dim3(128, 5, G), 256, 0, stream>>>(
            wqkv_b, region1, qkv_pre, O3, 0LL, CHW, 3LL * CHW);
        dwconv2<<<dim3(8, 384, G), 256, 0, stream>>>(
            qkv_pre, wdw, region1, 3LL * CHW, 2LL * CHW, 0);
        dwconv2<<<dim3(8, 192, G), 256, 0, stream>>>(
            qkv_pre + 2LL * CHW, wdw, qkv_pre, 3LL * CHW, 3LL * CHW, 384);
        attn_scores<<<dim3(16, 4, G), 256, 0, stream>>>(region1, S, norms, g0 * 4);
        softmax_k<<<4 * G, 64, 0, stream>>>(S, norms, temp, attn, g0 * 4);
        mproj<<<dim3(4, G), 256, 0, stream>>>(wproj, attn, Mm, g0);
        transpose_b<<<dim3(256, 3, G), 256, 0, stream>>>(
            qkv_pre, qkv_pre + CHW, 3LL * CHW, 3LL * CHW);
        gemm_bt<true><<<dim3(128, 2, G), 256, 0, stream>>>(
            Mm + (long long)g0 * 36864, qkv_pre + CHW, out + (long long)g0 * CHW,
            CD, 36864LL, 3LL * CHW, CHW);
    }
}